// Round 10
// baseline (2988.653 us; speedup 1.0000x reference)
//
#include <hip/hip_runtime.h>
#include <hip/hip_bf16.h>

typedef __attribute__((ext_vector_type(8))) short short8;
typedef __attribute__((ext_vector_type(4))) float f32x4;
typedef unsigned int u32;
typedef unsigned short u16;

#define T_STEPS 512
#define B_SZ    128
#define I_SZ    512
#define U_SZ    1024
#define K_TOT   1536   // 512 x-part + 1024 h-part

// ws layout (bytes)
#define XB_OFF   0            // X as bf16 [B][T][I] = 67,108,864 B
#define WC_OFF   67108864     // W packed [gcol][k] bf16 = 12,582,912 B
#define FLAG_OFF 79691776     // 256 u32 flags (4 clusters x 64)
#define HBUF_OFF 79708160     // [2][128][1024] bf16 = 524,288 B
// total 80,232,448 B

__device__ __forceinline__ u16 f2bf(float f) {
  u32 u = __float_as_uint(f);
  u32 r = (u + 0x7fffu + ((u >> 16) & 1u)) >> 16;   // RNE; inputs finite
  return (u16)r;
}
__device__ __forceinline__ float sigm(float x) { return 1.f / (1.f + __expf(-x)); }
__device__ __forceinline__ float tanh_s(float x) {
  float ax = fabsf(x);
  float e  = __expf(-2.f * ax);
  float t  = (1.f - e) / (1.f + e);
  return copysignf(t, x);
}

// ---- prep kernels ---------------------------------------------------------
__global__ void k_convX(const float* __restrict__ X, u16* __restrict__ Xb) {
  u32 i = blockIdx.x * 256u + threadIdx.x;            // covers 8,388,608 exactly
  float4 v = reinterpret_cast<const float4*>(X)[i];
  uint2 o;
  o.x = (u32)f2bf(v.x) | ((u32)f2bf(v.y) << 16);
  o.y = (u32)f2bf(v.z) | ((u32)f2bf(v.w) << 16);
  reinterpret_cast<uint2*>(Xb)[i] = o;
}

__global__ void k_packW(const float* __restrict__ Wih, const float* __restrict__ Whh,
                        u16* __restrict__ Wc) {
  const int gcol = blockIdx.x;
  for (int k = threadIdx.x; k < K_TOT; k += 256) {
    float v = (k < I_SZ) ? Wih[(size_t)gcol * I_SZ + k]
                         : Whh[(size_t)gcol * U_SZ + (k - I_SZ)];
    Wc[(size_t)gcol * K_TOT + k] = f2bf(v);
  }
}

__global__ void k_zero(u32* __restrict__ hz, u32* __restrict__ flags) {
  u32 i = blockIdx.x * 256u + threadIdx.x;            // 513 blocks
  if (i < 131072u)      hz[i] = 0u;                   // both h buffers
  else if (i < 131328u) flags[i - 131072u] = 0u;      // 256 flags
}

// ---- communication primitives (R2/R3/R6-proven) ---------------------------
__device__ __forceinline__ short8 ld_h16(const u16* p) {
  short8 r;
  asm volatile("global_load_dwordx4 %0, %1, off sc0 sc1" : "=v"(r) : "v"(p));
  return r;   // NOT ready until s_waitcnt vmcnt(0)
}
__device__ __forceinline__ void st_h(u16* p, u32 v) {
  asm volatile("global_store_short %0, %1, off sc0 sc1" :: "v"(p), "v"(v) : "memory");
}
__device__ __forceinline__ short8 ld_w16(const u16* p) {
  short8 r;
  asm volatile("global_load_dwordx4 %0, %1, off" : "=v"(r) : "v"(p));
  return r;   // NOT ready until s_waitcnt vmcnt(0)
}

// ---- persistent scan ------------------------------------------------------
// 256 WGs x 512 thr, 1 WG/CU. cluster cl = wg>>6 (4 clusters x 32 batch rows,
// independent). wloc = wg&63 -> u0 = wloc*16 (64 gate-cols = 4g x 16u).
// Waves: kw = wid (8-way K split, 192 K each). Per wave 48 MFMA.
// NEW vs R6: (1) each wave polls ONLY its 8 producer WGs' flags;
//            (2) next-step x-phase runs between st_h and the ACK drain.
__global__ __launch_bounds__(512, 2)
void lstm_scan(const u16* __restrict__ Xb, const u16* __restrict__ Wc,
               const float* __restrict__ bih, const float* __restrict__ bhh,
               u16* __restrict__ hbuf, u32* __restrict__ flags,
               float* __restrict__ out) {
  __shared__ __align__(16) float gbuf[8][64][36];     // [kw][col][row32+pad]

  const int tid  = threadIdx.x;
  const int wg   = blockIdx.x;
  const int cl   = wg >> 6;                           // cluster
  const int wloc = wg & 63;
  const int rb   = cl * 32;                           // batch row base
  const int u0   = wloc * 16;                         // unit base
  const int wid  = tid >> 6;
  const int lane = tid & 63;
  const int l15  = lane & 15;
  const int kg   = lane >> 4;
  const int kw   = wid;                               // 8-way K split

  // --- persistent W fragments (straight-line asm issue + wait: proven) ---
  short8 Bf[6][4];                                    // 96 regs
  #pragma unroll
  for (int ct = 0; ct < 4; ++ct) {
    const int gcol = ct * 1024 + u0 + l15;            // gate=ct, unit=u0+l15
    const u16* wrow = Wc + (size_t)gcol * K_TOT;
    #pragma unroll
    for (int i = 0; i < 6; ++i) {
      const int k = (i * 8 + kw) * 32 + kg * 8;
      Bf[i][ct] = ld_w16(wrow + k);
    }
  }
  asm volatile("s_waitcnt vmcnt(0)" ::: "memory");
  __builtin_amdgcn_sched_barrier(0);

  // --- cell ownership: thread -> (row rb+b_l, unit u0+uu) ---
  const int b_l = tid >> 4;                           // 0..31
  const int uu  = tid & 15;                           // 0..15
  const int ug  = u0 + uu;
  float bsum[4];
  #pragma unroll
  for (int g = 0; g < 4; ++g) bsum[g] = bih[g * 1024 + ug] + bhh[g * 1024 + ug];
  float c_state = 0.f;
  float* orow = out + (size_t)(rb + b_l) * (T_STEPS * U_SZ) + ug;
  const int hidx = (rb + b_l) * U_SZ + ug;
  u32* myflag = flags + (cl << 6) + wloc;

  // --- fine-grained poll: wave kw depends on exactly 8 producer WGs:
  //     wloc_p = kw*2 + 16*ih + b (ih=0..3, b=0..1). lane&7 encodes (ih,b);
  //     lanes 8..63 duplicate lane&7's flag (harmless).
  const int pidx = (kw << 1) + (((lane >> 1) & 3) << 4) + (lane & 1);
  const u32* pollp = flags + (cl << 6) + pidx;

  // --- A-operand rows (per wave: 2 row-tiles) ---
  const int r0 = rb + l15;
  const int r1 = r0 + 16;
  const u16* xrow0 = Xb + (size_t)r0 * (T_STEPS * I_SZ);
  const u16* xrow1 = Xb + (size_t)r1 * (T_STEPS * I_SZ);

  // --- accumulators live across iterations (x-phase pre-computed) ---
  f32x4 acc[2][4];
  #pragma unroll
  for (int rt = 0; rt < 2; ++rt)
    #pragma unroll
    for (int ct = 0; ct < 4; ++ct)
      acc[rt][ct] = (f32x4){0.f, 0.f, 0.f, 0.f};

  // prologue: x-phase for t = 0
  #pragma unroll
  for (int i = 0; i < 2; ++i) {
    const int k = (i * 8 + kw) * 32 + kg * 8;         // < 512
    const short8 a0 = *reinterpret_cast<const short8*>(xrow0 + k);
    const short8 a1 = *reinterpret_cast<const short8*>(xrow1 + k);
    #pragma unroll
    for (int ct = 0; ct < 4; ++ct) {
      acc[0][ct] = __builtin_amdgcn_mfma_f32_16x16x32_bf16(a0, Bf[i][ct], acc[0][ct], 0, 0, 0);
      acc[1][ct] = __builtin_amdgcn_mfma_f32_16x16x32_bf16(a1, Bf[i][ct], acc[1][ct], 0, 0, 0);
    }
  }

  for (int t = 0; t < T_STEPS; ++t) {
    const u16* hsrc = hbuf + ((t & 1) ^ 1) * (B_SZ * U_SZ);
    u16*       hdst = hbuf + (t & 1) * (B_SZ * U_SZ);

    // ---- wait: only this wave's 8 producers must have published t ----
    for (;;) {
      const u32 v = __hip_atomic_load(pollp, __ATOMIC_RELAXED, __HIP_MEMORY_SCOPE_AGENT);
      if (__all((int)(v >= (u32)t))) break;
      __builtin_amdgcn_s_sleep(1);
    }

    // ---- h-phase: batch all 8 L3 loads, one drain, then MFMA (R6-proven) ----
    short8 hA[4][2];
    #pragma unroll
    for (int ih = 0; ih < 4; ++ih) {
      const int ku = ((2 + ih) * 8 + kw) * 32 + kg * 8 - 512;   // 0..1023
      hA[ih][0] = ld_h16(hsrc + (size_t)r0 * U_SZ + ku);
      hA[ih][1] = ld_h16(hsrc + (size_t)r1 * U_SZ + ku);
    }
    asm volatile("s_waitcnt vmcnt(0)" ::: "memory");
    __builtin_amdgcn_sched_barrier(0);
    #pragma unroll
    for (int ih = 0; ih < 4; ++ih)
      #pragma unroll
      for (int ct = 0; ct < 4; ++ct) {
        acc[0][ct] = __builtin_amdgcn_mfma_f32_16x16x32_bf16(hA[ih][0], Bf[2 + ih][ct], acc[0][ct], 0, 0, 0);
        acc[1][ct] = __builtin_amdgcn_mfma_f32_16x16x32_bf16(hA[ih][1], Bf[2 + ih][ct], acc[1][ct], 0, 0, 0);
      }

    // ---- partials -> LDS (b128). C/D: col=lane&15, row=(lane>>4)*4+j ----
    #pragma unroll
    for (int rt = 0; rt < 2; ++rt)
      #pragma unroll
      for (int ct = 0; ct < 4; ++ct)
        *reinterpret_cast<float4*>(&gbuf[kw][ct * 16 + l15][rt * 16 + kg * 4]) =
            *reinterpret_cast<float4*>(&acc[rt][ct]);
    __syncthreads();                                  // (B) gbuf ready

    // ---- cell update: one (row, unit) per thread ----
    float gs[4];
    #pragma unroll
    for (int g = 0; g < 4; ++g) {
      float s = bsum[g];
      #pragma unroll
      for (int k2 = 0; k2 < 8; ++k2) s += gbuf[k2][g * 16 + uu][b_l];
      gs[g] = s;
    }
    const float ig = sigm(gs[0]);
    const float fg = sigm(gs[1]);
    const float gg = tanh_s(gs[2]);
    const float og = sigm(gs[3]);
    c_state = fg * c_state + ig * gg;
    const float h = og * tanh_s(c_state);

    // ---- publish: issue h store, then hide its ACK under t+1's x-phase ----
    st_h(hdst + hidx, (u32)f2bf(h));                  // bf16 h -> L3 (in flight)

    #pragma unroll
    for (int rt = 0; rt < 2; ++rt)
      #pragma unroll
      for (int ct = 0; ct < 4; ++ct)
        acc[rt][ct] = (f32x4){0.f, 0.f, 0.f, 0.f};
    if (t + 1 < T_STEPS) {                            // x-phase for t+1
      const u16* qx0 = xrow0 + (size_t)(t + 1) * I_SZ;
      const u16* qx1 = xrow1 + (size_t)(t + 1) * I_SZ;
      #pragma unroll
      for (int i = 0; i < 2; ++i) {
        const int k = (i * 8 + kw) * 32 + kg * 8;     // < 512
        const short8 a0 = *reinterpret_cast<const short8*>(qx0 + k);
        const short8 a1 = *reinterpret_cast<const short8*>(qx1 + k);
        #pragma unroll
        for (int ct = 0; ct < 4; ++ct) {
          acc[0][ct] = __builtin_amdgcn_mfma_f32_16x16x32_bf16(a0, Bf[i][ct], acc[0][ct], 0, 0, 0);
          acc[1][ct] = __builtin_amdgcn_mfma_f32_16x16x32_bf16(a1, Bf[i][ct], acc[1][ct], 0, 0, 0);
        }
      }
    }
    __builtin_amdgcn_sched_barrier(0);                // pin x-phase above the drain

    // ---- drain own h store, then flag (R6-proven ordering) ----
    asm volatile("s_waitcnt vmcnt(0)" ::: "memory");
    __syncthreads();                                  // (C) all stores drained; WAR-protects gbuf
    if (tid == 0)
      __hip_atomic_store(myflag, (u32)(t + 1), __ATOMIC_RELAXED, __HIP_MEMORY_SCOPE_AGENT);

    orow[(size_t)t * U_SZ] = h;                       // fp32 out — off the critical chain
  }
}

// ---- launch ---------------------------------------------------------------
extern "C" void kernel_launch(void* const* d_in, const int* in_sizes, int n_in,
                              void* d_out, int out_size, void* d_ws, size_t ws_size,
                              hipStream_t stream) {
  const float* X   = (const float*)d_in[0];
  const float* Wih = (const float*)d_in[1];
  const float* Whh = (const float*)d_in[2];
  const float* bih = (const float*)d_in[3];
  const float* bhh = (const float*)d_in[4];
  float* out = (float*)d_out;
  char*  ws  = (char*)d_ws;

  u16* Xb    = (u16*)(ws + XB_OFF);
  u16* Wc    = (u16*)(ws + WC_OFF);
  u32* flags = (u32*)(ws + FLAG_OFF);
  u16* hbuf  = (u16*)(ws + HBUF_OFF);

  hipLaunchKernelGGL(k_convX, dim3(32768), dim3(256), 0, stream, X, Xb);
  hipLaunchKernelGGL(k_packW, dim3(4096), dim3(256), 0, stream, Wih, Whh, Wc);
  hipLaunchKernelGGL(k_zero,  dim3(513),  dim3(256), 0, stream, (u32*)hbuf, flags);

  void* args[] = {(void*)&Xb, (void*)&Wc, (void*)&bih, (void*)&bhh,
                  (void*)&hbuf, (void*)&flags, (void*)&out};
  hipLaunchCooperativeKernel((void*)lstm_scan, dim3(256), dim3(512), args, 0, stream);
}